// Round 4
// baseline (155.342 us; speedup 1.0000x reference)
//
#include <hip/hip_runtime.h>

#define HW      4096      // 64*64
#define W_DIM   64
#define C_IN    256
#define NK      25        // 5x5 taps
#define NQ      112       // kq padded 100 -> 112

typedef __bf16 bf16x4 __attribute__((ext_vector_type(4)));
typedef __bf16 bf16x8 __attribute__((ext_vector_type(8)));
typedef float  f32x4  __attribute__((ext_vector_type(4)));
typedef float  f32x2  __attribute__((ext_vector_type(2)));

static __device__ __forceinline__ unsigned short f2bf(float f) {
    unsigned x = __float_as_uint(f);
    return (unsigned short)((x + 0x7fffu + ((x >> 16) & 1u)) >> 16);   // RNE
}
static __device__ __forceinline__ float bflo2f(unsigned u) { return __uint_as_float(u << 16); }
static __device__ __forceinline__ float bfhi2f(unsigned u) { return __uint_as_float(u & 0xffff0000u); }

// ---------------------------------------------------------------------------
// Kernel 0: weight prep.
//  wtb[tap][kq=112 zero-pad][c=64] bf16   (encoder B panels)
//  wct[cc=64][c=256] bf16                 (compress B)
__global__ __launch_bounds__(256) void k_prep(const float* __restrict__ wenc,
                                              const float* __restrict__ wcomp,
                                              unsigned short* __restrict__ wtb,
                                              unsigned short* __restrict__ wct) {
    int idx = blockIdx.x * 256 + threadIdx.x;   // 64512 + 16384 = 80896
    if (idx < 64512) {
        int c = idx & 63;
        int t2 = idx >> 6;
        int kq = t2 % NQ;
        int tap = t2 / NQ;
        float v = (kq < 100) ? wenc[(kq * 64 + c) * 9 + tap] : 0.0f;
        wtb[idx] = f2bf(v);
    } else if (idx < 80896) {
        int j = idx - 64512;
        wct[j] = f2bf(wcomp[j]);
    }
}

// ---------------------------------------------------------------------------
// Kernel 1: MFMA 1x1 compress. GEMM M=64 px (contig p), N=64 cc, K=256 c.
// Round-1 verified version, byte-identical (256 thr; r2/r3 widening hurt).
__global__ __launch_bounds__(256) void k_compress(const float* __restrict__ x,
        const unsigned short* __restrict__ wct, const float* __restrict__ bcomp,
        unsigned short* __restrict__ comp) {
    __shared__ unsigned short As[64 * 260];     // 33,280 B
    __shared__ unsigned short Bs[64 * 260];     // 33,280 B
    __shared__ float sbc[64];
    int n = blockIdx.y, p0 = blockIdx.x * 64;
    int tid = threadIdx.x, wv = tid >> 6, lane = tid & 63;
    int l15 = lane & 15, l4 = lane >> 4;
    if (tid < 64) sbc[tid] = bcomp[tid];

    const float* xp = x + (size_t)n * C_IN * HW + p0;
#pragma unroll
    for (int s = 0; s < 32; ++s) {              // A: 128 c-pairs x 64 px
        int cp = s * 4 + wv;                    // wave-uniform c-pair
        float a = xp[(size_t)(2 * cp) * HW + lane];
        float b = xp[(size_t)(2 * cp + 1) * HW + lane];
        unsigned pk = (unsigned)f2bf(a) | ((unsigned)f2bf(b) << 16);
        *(unsigned*)(As + lane * 260 + cp * 2) = pk;
    }
    const unsigned* wsrc = (const unsigned*)wct;
#pragma unroll
    for (int s = 0; s < 32; ++s) {              // B: 64 cc x 128 u32
        int slot = s * 256 + tid;
        int cc = slot >> 7, c2 = slot & 127;
        *(unsigned*)(Bs + cc * 260 + c2 * 2) = wsrc[cc * 128 + c2];
    }
    __syncthreads();

    f32x4 acc[4];
#pragma unroll
    for (int nt = 0; nt < 4; ++nt) acc[nt] = (f32x4){0.f, 0.f, 0.f, 0.f};
#pragma unroll
    for (int ck = 0; ck < 8; ++ck) {
        int ko = ck * 32 + l4 * 8;              // u16 offset in row
        bf16x4 alo = *(const bf16x4*)(As + (wv * 16 + l15) * 260 + ko);
        bf16x4 ahi = *(const bf16x4*)(As + (wv * 16 + l15) * 260 + ko + 4);
        bf16x8 af = __builtin_shufflevector(alo, ahi, 0, 1, 2, 3, 4, 5, 6, 7);
#pragma unroll
        for (int nt = 0; nt < 4; ++nt) {
            bf16x4 blo = *(const bf16x4*)(Bs + (nt * 16 + l15) * 260 + ko);
            bf16x4 bhi = *(const bf16x4*)(Bs + (nt * 16 + l15) * 260 + ko + 4);
            bf16x8 bfr = __builtin_shufflevector(blo, bhi, 0, 1, 2, 3, 4, 5, 6, 7);
            acc[nt] = __builtin_amdgcn_mfma_f32_16x16x32_bf16(af, bfr, acc[nt], 0, 0, 0);
        }
    }
    unsigned short* op = comp + ((size_t)n * HW + p0 + wv * 16 + l4 * 4) * 64;
#pragma unroll
    for (int reg = 0; reg < 4; ++reg)
#pragma unroll
        for (int nt = 0; nt < 4; ++nt) {
            int cc = nt * 16 + l15;
            op[(size_t)reg * 64 + cc] = f2bf(acc[nt][reg] + sbc[cc]);
        }
}

// ---------------------------------------------------------------------------
// Kernel 2: MFMA 3x3 encoder (64->100) + fused softmax. 8x8 tiles.
// Round-1 verified structure (256 thr, bf16 mask out). Only change: flat
// 256-block grid with XCD swizzle -> each XCD owns 32 consecutive work-ids
// (4 contiguous tile-rows of one n) so comp-halo overlap between vertical
// neighbors (+-8 tiles) stays in the local L2.
#define CREC    136
#define SB0     13600                // 100 px * 136
#define BSTRIDE 15232                // 112 * 136
#define EPI_PAD 116
__global__ __launch_bounds__(256) void k_enc(
        const unsigned short* __restrict__ comp,
        const unsigned short* __restrict__ wtb,
        const float* __restrict__ benc,
        unsigned short* __restrict__ mask) {
    __shared__ __align__(16) unsigned char smem[SB0 + 2 * BSTRIDE];   // 44,064 B
    __shared__ float sbias[NQ];
    int b = blockIdx.x;
    int nf = (b & 7) * 32 + (b >> 3);           // XCD-contiguous work ids
    int n = nf >> 6, tile = nf & 63;
    int h0 = (tile >> 3) * 8, w0 = (tile & 7) * 8;
    int tid = threadIdx.x, wv = tid >> 6, lane = tid & 63;
    int l15 = lane & 15, l4 = lane >> 4;
    if (tid < NQ) sbias[tid] = (tid < 100) ? benc[tid] : 0.0f;

    // stage comp halo: 100 px x 128 B, zero OOB (conv zero-pad)
    const uint4* csrc = (const uint4*)(comp + (size_t)n * HW * 64);
#pragma unroll
    for (int pass = 0; pass < 4; ++pass) {
        int s = pass * 256 + tid;               // 800 slots
        if (s < 800) {
            int px = s >> 3, j = s & 7;
            int gh = h0 + px / 10 - 1, gw = w0 + px % 10 - 1;
            uint4 v = make_uint4(0u, 0u, 0u, 0u);
            if ((unsigned)gh < 64u && (unsigned)gw < 64u)
                v = csrc[(size_t)(gh * 64 + gw) * 8 + j];
            *(uint2*)(smem + px * CREC + j * 16)     = make_uint2(v.x, v.y);
            *(uint2*)(smem + px * CREC + j * 16 + 8) = make_uint2(v.z, v.w);
        }
    }
    // stage B(0) -> buf0; preload B(1) -> regs
    {
        const uint4* bs = (const uint4*)wtb;
#pragma unroll
        for (int pass = 0; pass < 4; ++pass) {
            int s = pass * 256 + tid;           // 896 slots
            if (s < 896) {
                uint4 v = bs[s];
                int kq = s >> 3, j = s & 7;
                *(uint2*)(smem + SB0 + kq * CREC + j * 16)     = make_uint2(v.x, v.y);
                *(uint2*)(smem + SB0 + kq * CREC + j * 16 + 8) = make_uint2(v.z, v.w);
            }
        }
    }
    uint4 pre[4];
    {
        const uint4* bs = (const uint4*)(wtb + (size_t)1 * NQ * 64);
#pragma unroll
        for (int pass = 0; pass < 4; ++pass) {
            int s = pass * 256 + tid;
            if (s < 896) pre[pass] = bs[s];
        }
    }

    f32x4 acc[7];
#pragma unroll
    for (int nt = 0; nt < 7; ++nt) acc[nt] = (f32x4){0.f, 0.f, 0.f, 0.f};
    int r_t = 2 * wv + (l15 >> 3), cl = l15 & 7;

    for (int tap = 0; tap < 9; ++tap) {
        __syncthreads();                        // separates buf reads(t-1) from writes(t+1)
        if (tap < 8) {
            unsigned char* nbuf = smem + SB0 + ((tap + 1) & 1) * BSTRIDE;
#pragma unroll
            for (int pass = 0; pass < 4; ++pass) {
                int s = pass * 256 + tid;
                if (s < 896) {
                    int kq = s >> 3, j = s & 7;
                    *(uint2*)(nbuf + kq * CREC + j * 16)     = make_uint2(pre[pass].x, pre[pass].y);
                    *(uint2*)(nbuf + kq * CREC + j * 16 + 8) = make_uint2(pre[pass].z, pre[pass].w);
                }
            }
            if (tap < 7) {
                const uint4* bs = (const uint4*)(wtb + (size_t)(tap + 2) * NQ * 64);
#pragma unroll
                for (int pass = 0; pass < 4; ++pass) {
                    int s = pass * 256 + tid;
                    if (s < 896) pre[pass] = bs[s];
                }
            }
        }
        int ti = tap / 3, tj = tap % 3;
        int apx = (r_t + ti) * 10 + cl + tj;
        const unsigned char* cbuf = smem + SB0 + (tap & 1) * BSTRIDE;
#pragma unroll
        for (int ck = 0; ck < 2; ++ck) {
            int ko = ck * 64 + l4 * 16;         // byte offset in record
            bf16x4 alo = *(const bf16x4*)(smem + apx * CREC + ko);
            bf16x4 ahi = *(const bf16x4*)(smem + apx * CREC + ko + 8);
            bf16x8 af = __builtin_shufflevector(alo, ahi, 0, 1, 2, 3, 4, 5, 6, 7);
#pragma unroll
            for (int nt = 0; nt < 7; ++nt) {
                bf16x4 blo = *(const bf16x4*)(cbuf + (nt * 16 + l15) * CREC + ko);
                bf16x4 bhi = *(const bf16x4*)(cbuf + (nt * 16 + l15) * CREC + ko + 8);
                bf16x8 bfr = __builtin_shufflevector(blo, bhi, 0, 1, 2, 3, 4, 5, 6, 7);
                acc[nt] = __builtin_amdgcn_mfma_f32_16x16x32_bf16(af, bfr, acc[nt], 0, 0, 0);
            }
        }
    }
    __syncthreads();                            // B buffers dead; epilogue overlays

    float* smE = (float*)(smem + SB0) + (size_t)wv * 16 * EPI_PAD;
    unsigned short* maskn = mask + (size_t)n * HW * 100;
#pragma unroll
    for (int nt = 0; nt < 7; ++nt) {
        f32x4 v = acc[nt];
#pragma unroll
        for (int reg = 0; reg < 4; ++reg)
            smE[(l4 * 4 + reg) * EPI_PAD + nt * 16 + l15] = v[reg];
    }
    {
        int spx = lane >> 2, q = lane & 3;
        float* row = smE + spx * EPI_PAD;
        float v[NK], mx = -1e30f;
#pragma unroll
        for (int k = 0; k < NK; ++k) {
            v[k] = row[4 * k + q] + sbias[4 * k + q];
            mx = fmaxf(mx, v[k]);
        }
        float ssum = 0.f;
#pragma unroll
        for (int k = 0; k < NK; ++k) { v[k] = __expf(v[k] - mx); ssum += v[k]; }
        float inv = 1.0f / ssum;
#pragma unroll
        for (int k = 0; k < NK; ++k) row[4 * k + q] = v[k] * inv;
    }
#pragma unroll
    for (int i = 0; i < 7; ++i) {
        int idx = i * 64 + lane;                // 400 slots
        if (idx < 400) {
            int spx = idx / 25, f4 = idx % 25;
            int rr = 2 * wv + (spx >> 3), cc2 = spx & 7;
            size_t p = (size_t)(h0 + rr) * 64 + (w0 + cc2);
            const float* sp = smE + spx * EPI_PAD + f4 * 4;
            unsigned u0 = (unsigned)f2bf(sp[0]) | ((unsigned)f2bf(sp[1]) << 16);
            unsigned u1 = (unsigned)f2bf(sp[2]) | ((unsigned)f2bf(sp[3]) << 16);
            *(uint2*)(maskn + p * 100 + f4 * 4) = make_uint2(u0, u1);
        }
    }
}

// ---------------------------------------------------------------------------
// Kernel 4: reassembly v4 (round-1 verified). 8x8 px tile x 16 c, flat grid
// 4096 blocks, 6 blocks/CU (24 waves). XCD-aware swizzle. Mask bf16.
// Only change vs round 1: MSTR2 108 -> 110 (55 dwords, odd -> ms uint2
// reads spread across all 32 banks; 108 = 54 dw even aliased lanes
// {px, px+16, px+32, px+48} onto the same even-bank pair = 4-way).
#define XSTR2 20
#define MSTR2 110
__global__ __launch_bounds__(256, 6) void k_reassemble(const float* __restrict__ x,
        const unsigned short* __restrict__ mask, float* __restrict__ out) {
    __shared__ __align__(16) float xs[144 * XSTR2];         // 11,520 B
    __shared__ __align__(16) unsigned short ms[64 * MSTR2]; // 14,080 B
    int flat = blockIdx.x;
    int nf = (flat & 7) * 512 + (flat >> 3);    // XCD-contiguous work ids
    int tile = nf & 63, cg = (nf >> 6) & 15, n = nf >> 10;
    int h0 = (tile >> 3) * 8, w0 = (tile & 7) * 8;
    int tid = threadIdx.x;

    // stage x halo: 12x12 px x 16 c, float2 (gw base even -> pairs never
    // straddle the zero-pad boundary), zero OOB
    const float* xb = x + ((size_t)n * C_IN + cg * 16) * HW;
#pragma unroll
    for (int i = 0; i < 5; ++i) {
        int s = i * 256 + tid;                  // 16c * 12r * 6 pairs = 1152
        if (s < 1152) {
            int c = s / 72, rem = s % 72;
            int r = rem / 6, j = rem % 6;
            int gh = h0 - 2 + r, gw = w0 - 2 + j * 2;
            float2 v = make_float2(0.f, 0.f);
            if ((unsigned)gh < 64u && (unsigned)gw < 64u)
                v = *(const float2*)(xb + (size_t)c * HW + gh * W_DIM + gw);
            int px = r * 12 + j * 2;
            xs[px * XSTR2 + c]       = v.x;
            xs[(px + 1) * XSTR2 + c] = v.y;
        }
    }
    // stage mask: 64 px x 100 bf16, pure uint2 copy (conversion in k_enc)
    const unsigned short* mp = mask + (size_t)n * HW * 100;
#pragma unroll
    for (int i = 0; i < 7; ++i) {
        int s = i * 256 + tid;                  // 64 px * 25 quads = 1600
        if (s < 1600) {
            int px = s / 25, q = s % 25;
            int gp = (h0 + (px >> 3)) * W_DIM + w0 + (px & 7);
            *(uint2*)(ms + px * MSTR2 + q * 4) =
                *(const uint2*)(mp + (size_t)gp * 100 + q * 4);
        }
    }
    __syncthreads();

    int px = tid & 63, w = tid >> 6;            // lane = out px, wave = 4-ch slice
    int wx = px & 7, hy = px >> 3;
    f32x4 acc0 = {0.f, 0.f, 0.f, 0.f}, acc1 = {0.f, 0.f, 0.f, 0.f};
    f32x4 acc2 = {0.f, 0.f, 0.f, 0.f}, acc3 = {0.f, 0.f, 0.f, 0.f};
    const unsigned short* mrow = ms + px * MSTR2;
#pragma unroll
    for (int di = 0; di < 5; ++di)
#pragma unroll
        for (int dj = 0; dj < 5; ++dj) {
            int t = di * 5 + dj;
            uint2 mw = *(const uint2*)(mrow + t * 4);
            f32x4 xv = *(const f32x4*)(xs + ((hy + di) * 12 + wx + dj) * XSTR2 + w * 4);
            acc0 += xv * bflo2f(mw.x);
            acc1 += xv * bfhi2f(mw.x);
            acc2 += xv * bflo2f(mw.y);
            acc3 += xv * bfhi2f(mw.y);
        }
#pragma unroll
    for (int u = 0; u < 4; ++u) {
        float* ob = out + (((size_t)n * C_IN + cg * 16 + w * 4 + u) * 128 + 2 * (h0 + hy)) * 128
                        + 2 * (w0 + wx);
        *(float2*)(ob)       = make_float2(acc0[u], acc1[u]);
        *(float2*)(ob + 128) = make_float2(acc2[u], acc3[u]);
    }
}

// ---------------------------------------------------------------------------
extern "C" void kernel_launch(void* const* d_in, const int* in_sizes, int n_in,
                              void* d_out, int out_size, void* d_ws, size_t ws_size,
                              hipStream_t stream) {
    const float* x      = (const float*)d_in[0];
    const float* w_comp = (const float*)d_in[1];
    const float* b_comp = (const float*)d_in[2];
    const float* w_enc  = (const float*)d_in[3];
    const float* b_enc  = (const float*)d_in[4];
    float* out = (float*)d_out;
    unsigned char* ws = (unsigned char*)d_ws;

    unsigned short* comp  = (unsigned short*)(ws);             // 4*4096*64*2  = 2,097,152 B
    unsigned short* wtb   = (unsigned short*)(ws + 2097152);   // 9*112*64*2   =   129,024 B
    unsigned short* wct   = (unsigned short*)(ws + 2226176);   // 64*256*2     =    32,768 B
    unsigned short* maskp = (unsigned short*)(ws + 2258944);   // 4*4096*100*2 = 3,276,800 B

    hipLaunchKernelGGL(k_prep,       dim3(316),      dim3(256), 0, stream,
                       w_enc, w_comp, wtb, wct);
    hipLaunchKernelGGL(k_compress,   dim3(64, 4),    dim3(256), 0, stream,
                       x, wct, b_comp, comp);
    hipLaunchKernelGGL(k_enc,        dim3(256),      dim3(256), 0, stream,
                       comp, wtb, b_enc, maskp);
    hipLaunchKernelGGL(k_reassemble, dim3(4096),     dim3(256), 0, stream,
                       x, maskp, out);
}

// Round 5
// 121.103 us; speedup vs baseline: 1.2827x; 1.2827x over previous
//
#include <hip/hip_runtime.h>

#define HW      4096      // 64*64
#define W_DIM   64
#define C_IN    256
#define NK      25        // 5x5 taps
#define NQ      112       // kq padded 100 -> 112

typedef __bf16 bf16x4 __attribute__((ext_vector_type(4)));
typedef __bf16 bf16x8 __attribute__((ext_vector_type(8)));
typedef float  f32x4  __attribute__((ext_vector_type(4)));
typedef float  f32x2  __attribute__((ext_vector_type(2)));

static __device__ __forceinline__ unsigned short f2bf(float f) {
    unsigned x = __float_as_uint(f);
    return (unsigned short)((x + 0x7fffu + ((x >> 16) & 1u)) >> 16);   // RNE
}
static __device__ __forceinline__ float bflo2f(unsigned u) { return __uint_as_float(u << 16); }
static __device__ __forceinline__ float bfhi2f(unsigned u) { return __uint_as_float(u & 0xffff0000u); }

// ---------------------------------------------------------------------------
// Kernel 0: weight prep.
//  wtb[tap][kq=112 zero-pad][c=64] bf16   (encoder B panels)
//  wct[cc=64][c=256] bf16                 (compress B)
__global__ __launch_bounds__(256) void k_prep(const float* __restrict__ wenc,
                                              const float* __restrict__ wcomp,
                                              unsigned short* __restrict__ wtb,
                                              unsigned short* __restrict__ wct) {
    int idx = blockIdx.x * 256 + threadIdx.x;   // 64512 + 16384 = 80896
    if (idx < 64512) {
        int c = idx & 63;
        int t2 = idx >> 6;
        int kq = t2 % NQ;
        int tap = t2 / NQ;
        float v = (kq < 100) ? wenc[(kq * 64 + c) * 9 + tap] : 0.0f;
        wtb[idx] = f2bf(v);
    } else if (idx < 80896) {
        int j = idx - 64512;
        wct[j] = f2bf(wcomp[j]);
    }
}

// ---------------------------------------------------------------------------
// Kernel 1: MFMA 1x1 compress. GEMM M=64 px (contig p), N=64 cc, K=256 c.
// Round-1 verified version, byte-identical (256 thr; r2/r3 widening hurt).
__global__ __launch_bounds__(256) void k_compress(const float* __restrict__ x,
        const unsigned short* __restrict__ wct, const float* __restrict__ bcomp,
        unsigned short* __restrict__ comp) {
    __shared__ unsigned short As[64 * 260];     // 33,280 B
    __shared__ unsigned short Bs[64 * 260];     // 33,280 B
    __shared__ float sbc[64];
    int n = blockIdx.y, p0 = blockIdx.x * 64;
    int tid = threadIdx.x, wv = tid >> 6, lane = tid & 63;
    int l15 = lane & 15, l4 = lane >> 4;
    if (tid < 64) sbc[tid] = bcomp[tid];

    const float* xp = x + (size_t)n * C_IN * HW + p0;
#pragma unroll
    for (int s = 0; s < 32; ++s) {              // A: 128 c-pairs x 64 px
        int cp = s * 4 + wv;                    // wave-uniform c-pair
        float a = xp[(size_t)(2 * cp) * HW + lane];
        float b = xp[(size_t)(2 * cp + 1) * HW + lane];
        unsigned pk = (unsigned)f2bf(a) | ((unsigned)f2bf(b) << 16);
        *(unsigned*)(As + lane * 260 + cp * 2) = pk;
    }
    const unsigned* wsrc = (const unsigned*)wct;
#pragma unroll
    for (int s = 0; s < 32; ++s) {              // B: 64 cc x 128 u32
        int slot = s * 256 + tid;
        int cc = slot >> 7, c2 = slot & 127;
        *(unsigned*)(Bs + cc * 260 + c2 * 2) = wsrc[cc * 128 + c2];
    }
    __syncthreads();

    f32x4 acc[4];
#pragma unroll
    for (int nt = 0; nt < 4; ++nt) acc[nt] = (f32x4){0.f, 0.f, 0.f, 0.f};
#pragma unroll
    for (int ck = 0; ck < 8; ++ck) {
        int ko = ck * 32 + l4 * 8;              // u16 offset in row
        bf16x4 alo = *(const bf16x4*)(As + (wv * 16 + l15) * 260 + ko);
        bf16x4 ahi = *(const bf16x4*)(As + (wv * 16 + l15) * 260 + ko + 4);
        bf16x8 af = __builtin_shufflevector(alo, ahi, 0, 1, 2, 3, 4, 5, 6, 7);
#pragma unroll
        for (int nt = 0; nt < 4; ++nt) {
            bf16x4 blo = *(const bf16x4*)(Bs + (nt * 16 + l15) * 260 + ko);
            bf16x4 bhi = *(const bf16x4*)(Bs + (nt * 16 + l15) * 260 + ko + 4);
            bf16x8 bfr = __builtin_shufflevector(blo, bhi, 0, 1, 2, 3, 4, 5, 6, 7);
            acc[nt] = __builtin_amdgcn_mfma_f32_16x16x32_bf16(af, bfr, acc[nt], 0, 0, 0);
        }
    }
    unsigned short* op = comp + ((size_t)n * HW + p0 + wv * 16 + l4 * 4) * 64;
#pragma unroll
    for (int reg = 0; reg < 4; ++reg)
#pragma unroll
        for (int nt = 0; nt < 4; ++nt) {
            int cc = nt * 16 + l15;
            op[(size_t)reg * 64 + cc] = f2bf(acc[nt][reg] + sbc[cc]);
        }
}

// ---------------------------------------------------------------------------
// Kernel 2: MFMA 3x3 encoder (64->100) + fused softmax. 8x8 tiles, grid (64,4).
// Round-1 verified version, byte-identical (bf16 mask out; r4's swizzle
// experiment dropped -- unattributed, reverted).
#define CREC    136
#define SB0     13600                // 100 px * 136
#define BSTRIDE 15232                // 112 * 136
#define EPI_PAD 116
__global__ __launch_bounds__(256) void k_enc(
        const unsigned short* __restrict__ comp,
        const unsigned short* __restrict__ wtb,
        const float* __restrict__ benc,
        unsigned short* __restrict__ mask) {
    __shared__ __align__(16) unsigned char smem[SB0 + 2 * BSTRIDE];   // 44,064 B
    __shared__ float sbias[NQ];
    int n = blockIdx.y, tile = blockIdx.x;
    int h0 = (tile >> 3) * 8, w0 = (tile & 7) * 8;
    int tid = threadIdx.x, wv = tid >> 6, lane = tid & 63;
    int l15 = lane & 15, l4 = lane >> 4;
    if (tid < NQ) sbias[tid] = (tid < 100) ? benc[tid] : 0.0f;

    // stage comp halo: 100 px x 128 B, zero OOB (conv zero-pad)
    const uint4* csrc = (const uint4*)(comp + (size_t)n * HW * 64);
#pragma unroll
    for (int pass = 0; pass < 4; ++pass) {
        int s = pass * 256 + tid;               // 800 slots
        if (s < 800) {
            int px = s >> 3, j = s & 7;
            int gh = h0 + px / 10 - 1, gw = w0 + px % 10 - 1;
            uint4 v = make_uint4(0u, 0u, 0u, 0u);
            if ((unsigned)gh < 64u && (unsigned)gw < 64u)
                v = csrc[(size_t)(gh * 64 + gw) * 8 + j];
            *(uint2*)(smem + px * CREC + j * 16)     = make_uint2(v.x, v.y);
            *(uint2*)(smem + px * CREC + j * 16 + 8) = make_uint2(v.z, v.w);
        }
    }
    // stage B(0) -> buf0; preload B(1) -> regs
    {
        const uint4* bs = (const uint4*)wtb;
#pragma unroll
        for (int pass = 0; pass < 4; ++pass) {
            int s = pass * 256 + tid;           // 896 slots
            if (s < 896) {
                uint4 v = bs[s];
                int kq = s >> 3, j = s & 7;
                *(uint2*)(smem + SB0 + kq * CREC + j * 16)     = make_uint2(v.x, v.y);
                *(uint2*)(smem + SB0 + kq * CREC + j * 16 + 8) = make_uint2(v.z, v.w);
            }
        }
    }
    uint4 pre[4];
    {
        const uint4* bs = (const uint4*)(wtb + (size_t)1 * NQ * 64);
#pragma unroll
        for (int pass = 0; pass < 4; ++pass) {
            int s = pass * 256 + tid;
            if (s < 896) pre[pass] = bs[s];
        }
    }

    f32x4 acc[7];
#pragma unroll
    for (int nt = 0; nt < 7; ++nt) acc[nt] = (f32x4){0.f, 0.f, 0.f, 0.f};
    int r_t = 2 * wv + (l15 >> 3), cl = l15 & 7;

    for (int tap = 0; tap < 9; ++tap) {
        __syncthreads();                        // separates buf reads(t-1) from writes(t+1)
        if (tap < 8) {
            unsigned char* nbuf = smem + SB0 + ((tap + 1) & 1) * BSTRIDE;
#pragma unroll
            for (int pass = 0; pass < 4; ++pass) {
                int s = pass * 256 + tid;
                if (s < 896) {
                    int kq = s >> 3, j = s & 7;
                    *(uint2*)(nbuf + kq * CREC + j * 16)     = make_uint2(pre[pass].x, pre[pass].y);
                    *(uint2*)(nbuf + kq * CREC + j * 16 + 8) = make_uint2(pre[pass].z, pre[pass].w);
                }
            }
            if (tap < 7) {
                const uint4* bs = (const uint4*)(wtb + (size_t)(tap + 2) * NQ * 64);
#pragma unroll
                for (int pass = 0; pass < 4; ++pass) {
                    int s = pass * 256 + tid;
                    if (s < 896) pre[pass] = bs[s];
                }
            }
        }
        int ti = tap / 3, tj = tap % 3;
        int apx = (r_t + ti) * 10 + cl + tj;
        const unsigned char* cbuf = smem + SB0 + (tap & 1) * BSTRIDE;
#pragma unroll
        for (int ck = 0; ck < 2; ++ck) {
            int ko = ck * 64 + l4 * 16;         // byte offset in record
            bf16x4 alo = *(const bf16x4*)(smem + apx * CREC + ko);
            bf16x4 ahi = *(const bf16x4*)(smem + apx * CREC + ko + 8);
            bf16x8 af = __builtin_shufflevector(alo, ahi, 0, 1, 2, 3, 4, 5, 6, 7);
#pragma unroll
            for (int nt = 0; nt < 7; ++nt) {
                bf16x4 blo = *(const bf16x4*)(cbuf + (nt * 16 + l15) * CREC + ko);
                bf16x4 bhi = *(const bf16x4*)(cbuf + (nt * 16 + l15) * CREC + ko + 8);
                bf16x8 bfr = __builtin_shufflevector(blo, bhi, 0, 1, 2, 3, 4, 5, 6, 7);
                acc[nt] = __builtin_amdgcn_mfma_f32_16x16x32_bf16(af, bfr, acc[nt], 0, 0, 0);
            }
        }
    }
    __syncthreads();                            // B buffers dead; epilogue overlays

    float* smE = (float*)(smem + SB0) + (size_t)wv * 16 * EPI_PAD;
    unsigned short* maskn = mask + (size_t)n * HW * 100;
#pragma unroll
    for (int nt = 0; nt < 7; ++nt) {
        f32x4 v = acc[nt];
#pragma unroll
        for (int reg = 0; reg < 4; ++reg)
            smE[(l4 * 4 + reg) * EPI_PAD + nt * 16 + l15] = v[reg];
    }
    {
        int spx = lane >> 2, q = lane & 3;
        float* row = smE + spx * EPI_PAD;
        float v[NK], mx = -1e30f;
#pragma unroll
        for (int k = 0; k < NK; ++k) {
            v[k] = row[4 * k + q] + sbias[4 * k + q];
            mx = fmaxf(mx, v[k]);
        }
        float ssum = 0.f;
#pragma unroll
        for (int k = 0; k < NK; ++k) { v[k] = __expf(v[k] - mx); ssum += v[k]; }
        float inv = 1.0f / ssum;
#pragma unroll
        for (int k = 0; k < NK; ++k) row[4 * k + q] = v[k] * inv;
    }
#pragma unroll
    for (int i = 0; i < 7; ++i) {
        int idx = i * 64 + lane;                // 400 slots
        if (idx < 400) {
            int spx = idx / 25, f4 = idx % 25;
            int rr = 2 * wv + (spx >> 3), cc2 = spx & 7;
            size_t p = (size_t)(h0 + rr) * 64 + (w0 + cc2);
            const float* sp = smE + spx * EPI_PAD + f4 * 4;
            unsigned u0 = (unsigned)f2bf(sp[0]) | ((unsigned)f2bf(sp[1]) << 16);
            unsigned u1 = (unsigned)f2bf(sp[2]) | ((unsigned)f2bf(sp[3]) << 16);
            *(uint2*)(maskn + p * 100 + f4 * 4) = make_uint2(u0, u1);
        }
    }
}

// ---------------------------------------------------------------------------
// Kernel 4: reassembly v5 = round-1 verified structure; ONLY change: ms is
// u32[64 rows][51 dw] (odd dword stride, gcd(51? -> 51 mod 32 = 19, gcd=1)
// -> lane px maps to all 32 banks, 2 lanes/bank = free per m136), and mask
// values are read as two b32 loads (no 8B alignment constraint; same LDS
// data cycles as one b64: 2x2 vs 1x4). r4 taught: b64 needs 8B-aligned row
// stride, which forces even dw stride, which forces >=4-way aliasing --
// b32 + odd stride is the only conflict-free point. LDS 24,576 B.
#define XSTR2 20
#define MROW  51
__global__ __launch_bounds__(256, 6) void k_reassemble(const float* __restrict__ x,
        const unsigned short* __restrict__ mask, float* __restrict__ out) {
    __shared__ __align__(16) float xs[144 * XSTR2];   // 11,520 B
    __shared__ unsigned msu[64 * MROW];               // 13,056 B
    int flat = blockIdx.x;
    int nf = (flat & 7) * 512 + (flat >> 3);    // XCD-contiguous work ids
    int tile = nf & 63, cg = (nf >> 6) & 15, n = nf >> 10;
    int h0 = (tile >> 3) * 8, w0 = (tile & 7) * 8;
    int tid = threadIdx.x;

    // stage x halo: 12x12 px x 16 c, float2 (gw base even -> pairs never
    // straddle the zero-pad boundary), zero OOB
    const float* xb = x + ((size_t)n * C_IN + cg * 16) * HW;
#pragma unroll
    for (int i = 0; i < 5; ++i) {
        int s = i * 256 + tid;                  // 16c * 12r * 6 pairs = 1152
        if (s < 1152) {
            int c = s / 72, rem = s % 72;
            int r = rem / 6, j = rem % 6;
            int gh = h0 - 2 + r, gw = w0 - 2 + j * 2;
            float2 v = make_float2(0.f, 0.f);
            if ((unsigned)gh < 64u && (unsigned)gw < 64u)
                v = *(const float2*)(xb + (size_t)c * HW + gh * W_DIM + gw);
            int px = r * 12 + j * 2;
            xs[px * XSTR2 + c]       = v.x;
            xs[(px + 1) * XSTR2 + c] = v.y;
        }
    }
    // stage mask: 64 px x 100 bf16. Global reads unchanged (coalesced 200B
    // runs); LDS writes: same-px lanes hit dwords 2q apart -> <=2/bank, free.
    const unsigned short* mp = mask + (size_t)n * HW * 100;
#pragma unroll
    for (int i = 0; i < 7; ++i) {
        int s = i * 256 + tid;                  // 64 px * 25 quads = 1600
        if (s < 1600) {
            int px = s / 25, q = s % 25;
            int gp = (h0 + (px >> 3)) * W_DIM + w0 + (px & 7);
            uint2 v = *(const uint2*)(mp + (size_t)gp * 100 + q * 4);
            msu[px * MROW + 2 * q]     = v.x;
            msu[px * MROW + 2 * q + 1] = v.y;
        }
    }
    __syncthreads();

    int px = tid & 63, w = tid >> 6;            // lane = out px, wave = 4-ch slice
    int wx = px & 7, hy = px >> 3;
    f32x4 acc0 = {0.f, 0.f, 0.f, 0.f}, acc1 = {0.f, 0.f, 0.f, 0.f};
    f32x4 acc2 = {0.f, 0.f, 0.f, 0.f}, acc3 = {0.f, 0.f, 0.f, 0.f};
    const unsigned* mrow = msu + px * MROW;
#pragma unroll
    for (int di = 0; di < 5; ++di)
#pragma unroll
        for (int dj = 0; dj < 5; ++dj) {
            int t = di * 5 + dj;
            unsigned mx0 = mrow[2 * t];
            unsigned mx1 = mrow[2 * t + 1];
            f32x4 xv = *(const f32x4*)(xs + ((hy + di) * 12 + wx + dj) * XSTR2 + w * 4);
            acc0 += xv * bflo2f(mx0);
            acc1 += xv * bfhi2f(mx0);
            acc2 += xv * bflo2f(mx1);
            acc3 += xv * bfhi2f(mx1);
        }
#pragma unroll
    for (int u = 0; u < 4; ++u) {
        float* ob = out + (((size_t)n * C_IN + cg * 16 + w * 4 + u) * 128 + 2 * (h0 + hy)) * 128
                        + 2 * (w0 + wx);
        *(float2*)(ob)       = make_float2(acc0[u], acc1[u]);
        *(float2*)(ob + 128) = make_float2(acc2[u], acc3[u]);
    }
}

// ---------------------------------------------------------------------------
extern "C" void kernel_launch(void* const* d_in, const int* in_sizes, int n_in,
                              void* d_out, int out_size, void* d_ws, size_t ws_size,
                              hipStream_t stream) {
    const float* x      = (const float*)d_in[0];
    const float* w_comp = (const float*)d_in[1];
    const float* b_comp = (const float*)d_in[2];
    const float* w_enc  = (const float*)d_in[3];
    const float* b_enc  = (const float*)d_in[4];
    float* out = (float*)d_out;
    unsigned char* ws = (unsigned char*)d_ws;

    unsigned short* comp  = (unsigned short*)(ws);             // 4*4096*64*2  = 2,097,152 B
    unsigned short* wtb   = (unsigned short*)(ws + 2097152);   // 9*112*64*2   =   129,024 B
    unsigned short* wct   = (unsigned short*)(ws + 2226176);   // 64*256*2     =    32,768 B
    unsigned short* maskp = (unsigned short*)(ws + 2258944);   // 4*4096*100*2 = 3,276,800 B

    hipLaunchKernelGGL(k_prep,       dim3(316),      dim3(256), 0, stream,
                       w_enc, w_comp, wtb, wct);
    hipLaunchKernelGGL(k_compress,   dim3(64, 4),    dim3(256), 0, stream,
                       x, wct, b_comp, comp);
    hipLaunchKernelGGL(k_enc,        dim3(64, 4),    dim3(256), 0, stream,
                       comp, wtb, b_enc, maskp);
    hipLaunchKernelGGL(k_reassemble, dim3(4096),     dim3(256), 0, stream,
                       x, maskp, out);
}

// Round 6
// 119.941 us; speedup vs baseline: 1.2952x; 1.0097x over previous
//
#include <hip/hip_runtime.h>

#define HW      4096      // 64*64
#define W_DIM   64
#define C_IN    256
#define NK      25        // 5x5 taps
#define NQ      112       // kq padded 100 -> 112

typedef __bf16 bf16x4 __attribute__((ext_vector_type(4)));
typedef __bf16 bf16x8 __attribute__((ext_vector_type(8)));
typedef float  f32x4  __attribute__((ext_vector_type(4)));
typedef float  f32x2  __attribute__((ext_vector_type(2)));

static __device__ __forceinline__ unsigned short f2bf(float f) {
    unsigned x = __float_as_uint(f);
    return (unsigned short)((x + 0x7fffu + ((x >> 16) & 1u)) >> 16);   // RNE
}
static __device__ __forceinline__ float bflo2f(unsigned u) { return __uint_as_float(u << 16); }
static __device__ __forceinline__ float bfhi2f(unsigned u) { return __uint_as_float(u & 0xffff0000u); }

// ---------------------------------------------------------------------------
// Kernel 1: MFMA 1x1 compress (blocks 0..255) + wtb weight prep (blocks
// 256..507). Compress hot loop = round-1 verified, byte-identical; B is now
// staged straight from f32 wcomp with the same f2bf conversion k_prep used
// (wct buffer deleted). The 252 tail blocks write wtb[tap][kq][c] bf16 for
// k_enc (ordering via kernel boundary). Saves one launch.
__global__ __launch_bounds__(256) void k_compress(const float* __restrict__ x,
        const float* __restrict__ wcomp, const float* __restrict__ bcomp,
        const float* __restrict__ wenc,
        unsigned short* __restrict__ comp, unsigned short* __restrict__ wtb) {
    __shared__ unsigned short As[64 * 260];     // 33,280 B
    __shared__ unsigned short Bs[64 * 260];     // 33,280 B
    __shared__ float sbc[64];
    int b = blockIdx.x;
    int tid = threadIdx.x;
    if (b >= 256) {                             // ---- prep tail: wtb only
        int idx = (b - 256) * 256 + tid;        // 252*256 = 64512 exactly
        int c = idx & 63;
        int t2 = idx >> 6;
        int kq = t2 % NQ;
        int tap = t2 / NQ;
        float v = (kq < 100) ? wenc[(kq * 64 + c) * 9 + tap] : 0.0f;
        wtb[idx] = f2bf(v);
        return;
    }
    int n = b >> 6, p0 = (b & 63) * 64;
    int wv = tid >> 6, lane = tid & 63;
    int l15 = lane & 15, l4 = lane >> 4;
    if (tid < 64) sbc[tid] = bcomp[tid];

    const float* xp = x + (size_t)n * C_IN * HW + p0;
#pragma unroll
    for (int s = 0; s < 32; ++s) {              // A: 128 c-pairs x 64 px
        int cp = s * 4 + wv;                    // wave-uniform c-pair
        float a = xp[(size_t)(2 * cp) * HW + lane];
        float bb = xp[(size_t)(2 * cp + 1) * HW + lane];
        unsigned pk = (unsigned)f2bf(a) | ((unsigned)f2bf(bb) << 16);
        *(unsigned*)(As + lane * 260 + cp * 2) = pk;
    }
    const float2* wf = (const float2*)wcomp;    // B: convert f32 -> packed bf16
#pragma unroll
    for (int s = 0; s < 32; ++s) {              // 64 cc x 128 pair-slots
        int slot = s * 256 + tid;
        int cc = slot >> 7, c2 = slot & 127;
        float2 v = wf[cc * 128 + c2];           // coalesced, 8B-aligned
        unsigned pk = (unsigned)f2bf(v.x) | ((unsigned)f2bf(v.y) << 16);
        *(unsigned*)(Bs + cc * 260 + c2 * 2) = pk;
    }
    __syncthreads();

    f32x4 acc[4];
#pragma unroll
    for (int nt = 0; nt < 4; ++nt) acc[nt] = (f32x4){0.f, 0.f, 0.f, 0.f};
#pragma unroll
    for (int ck = 0; ck < 8; ++ck) {
        int ko = ck * 32 + l4 * 8;              // u16 offset in row
        bf16x4 alo = *(const bf16x4*)(As + (wv * 16 + l15) * 260 + ko);
        bf16x4 ahi = *(const bf16x4*)(As + (wv * 16 + l15) * 260 + ko + 4);
        bf16x8 af = __builtin_shufflevector(alo, ahi, 0, 1, 2, 3, 4, 5, 6, 7);
#pragma unroll
        for (int nt = 0; nt < 4; ++nt) {
            bf16x4 blo = *(const bf16x4*)(Bs + (nt * 16 + l15) * 260 + ko);
            bf16x4 bhi = *(const bf16x4*)(Bs + (nt * 16 + l15) * 260 + ko + 4);
            bf16x8 bfr = __builtin_shufflevector(blo, bhi, 0, 1, 2, 3, 4, 5, 6, 7);
            acc[nt] = __builtin_amdgcn_mfma_f32_16x16x32_bf16(af, bfr, acc[nt], 0, 0, 0);
        }
    }
    unsigned short* op = comp + ((size_t)n * HW + p0 + wv * 16 + l4 * 4) * 64;
#pragma unroll
    for (int reg = 0; reg < 4; ++reg)
#pragma unroll
        for (int nt = 0; nt < 4; ++nt) {
            int cc = nt * 16 + l15;
            op[(size_t)reg * 64 + cc] = f2bf(acc[nt][reg] + sbc[cc]);
        }
}

// ---------------------------------------------------------------------------
// Kernel 2: MFMA 3x3 encoder (64->100) + fused softmax. 8x8 tiles, grid (64,4).
// Round-1 verified version, byte-identical (bf16 mask out).
#define CREC    136
#define SB0     13600                // 100 px * 136
#define BSTRIDE 15232                // 112 * 136
#define EPI_PAD 116
__global__ __launch_bounds__(256) void k_enc(
        const unsigned short* __restrict__ comp,
        const unsigned short* __restrict__ wtb,
        const float* __restrict__ benc,
        unsigned short* __restrict__ mask) {
    __shared__ __align__(16) unsigned char smem[SB0 + 2 * BSTRIDE];   // 44,064 B
    __shared__ float sbias[NQ];
    int n = blockIdx.y, tile = blockIdx.x;
    int h0 = (tile >> 3) * 8, w0 = (tile & 7) * 8;
    int tid = threadIdx.x, wv = tid >> 6, lane = tid & 63;
    int l15 = lane & 15, l4 = lane >> 4;
    if (tid < NQ) sbias[tid] = (tid < 100) ? benc[tid] : 0.0f;

    // stage comp halo: 100 px x 128 B, zero OOB (conv zero-pad)
    const uint4* csrc = (const uint4*)(comp + (size_t)n * HW * 64);
#pragma unroll
    for (int pass = 0; pass < 4; ++pass) {
        int s = pass * 256 + tid;               // 800 slots
        if (s < 800) {
            int px = s >> 3, j = s & 7;
            int gh = h0 + px / 10 - 1, gw = w0 + px % 10 - 1;
            uint4 v = make_uint4(0u, 0u, 0u, 0u);
            if ((unsigned)gh < 64u && (unsigned)gw < 64u)
                v = csrc[(size_t)(gh * 64 + gw) * 8 + j];
            *(uint2*)(smem + px * CREC + j * 16)     = make_uint2(v.x, v.y);
            *(uint2*)(smem + px * CREC + j * 16 + 8) = make_uint2(v.z, v.w);
        }
    }
    // stage B(0) -> buf0; preload B(1) -> regs
    {
        const uint4* bs = (const uint4*)wtb;
#pragma unroll
        for (int pass = 0; pass < 4; ++pass) {
            int s = pass * 256 + tid;           // 896 slots
            if (s < 896) {
                uint4 v = bs[s];
                int kq = s >> 3, j = s & 7;
                *(uint2*)(smem + SB0 + kq * CREC + j * 16)     = make_uint2(v.x, v.y);
                *(uint2*)(smem + SB0 + kq * CREC + j * 16 + 8) = make_uint2(v.z, v.w);
            }
        }
    }
    uint4 pre[4];
    {
        const uint4* bs = (const uint4*)(wtb + (size_t)1 * NQ * 64);
#pragma unroll
        for (int pass = 0; pass < 4; ++pass) {
            int s = pass * 256 + tid;
            if (s < 896) pre[pass] = bs[s];
        }
    }

    f32x4 acc[7];
#pragma unroll
    for (int nt = 0; nt < 7; ++nt) acc[nt] = (f32x4){0.f, 0.f, 0.f, 0.f};
    int r_t = 2 * wv + (l15 >> 3), cl = l15 & 7;

    for (int tap = 0; tap < 9; ++tap) {
        __syncthreads();                        // separates buf reads(t-1) from writes(t+1)
        if (tap < 8) {
            unsigned char* nbuf = smem + SB0 + ((tap + 1) & 1) * BSTRIDE;
#pragma unroll
            for (int pass = 0; pass < 4; ++pass) {
                int s = pass * 256 + tid;
                if (s < 896) {
                    int kq = s >> 3, j = s & 7;
                    *(uint2*)(nbuf + kq * CREC + j * 16)     = make_uint2(pre[pass].x, pre[pass].y);
                    *(uint2*)(nbuf + kq * CREC + j * 16 + 8) = make_uint2(pre[pass].z, pre[pass].w);
                }
            }
            if (tap < 7) {
                const uint4* bs = (const uint4*)(wtb + (size_t)(tap + 2) * NQ * 64);
#pragma unroll
                for (int pass = 0; pass < 4; ++pass) {
                    int s = pass * 256 + tid;
                    if (s < 896) pre[pass] = bs[s];
                }
            }
        }
        int ti = tap / 3, tj = tap % 3;
        int apx = (r_t + ti) * 10 + cl + tj;
        const unsigned char* cbuf = smem + SB0 + (tap & 1) * BSTRIDE;
#pragma unroll
        for (int ck = 0; ck < 2; ++ck) {
            int ko = ck * 64 + l4 * 16;         // byte offset in record
            bf16x4 alo = *(const bf16x4*)(smem + apx * CREC + ko);
            bf16x4 ahi = *(const bf16x4*)(smem + apx * CREC + ko + 8);
            bf16x8 af = __builtin_shufflevector(alo, ahi, 0, 1, 2, 3, 4, 5, 6, 7);
#pragma unroll
            for (int nt = 0; nt < 7; ++nt) {
                bf16x4 blo = *(const bf16x4*)(cbuf + (nt * 16 + l15) * CREC + ko);
                bf16x4 bhi = *(const bf16x4*)(cbuf + (nt * 16 + l15) * CREC + ko + 8);
                bf16x8 bfr = __builtin_shufflevector(blo, bhi, 0, 1, 2, 3, 4, 5, 6, 7);
                acc[nt] = __builtin_amdgcn_mfma_f32_16x16x32_bf16(af, bfr, acc[nt], 0, 0, 0);
            }
        }
    }
    __syncthreads();                            // B buffers dead; epilogue overlays

    float* smE = (float*)(smem + SB0) + (size_t)wv * 16 * EPI_PAD;
    unsigned short* maskn = mask + (size_t)n * HW * 100;
#pragma unroll
    for (int nt = 0; nt < 7; ++nt) {
        f32x4 v = acc[nt];
#pragma unroll
        for (int reg = 0; reg < 4; ++reg)
            smE[(l4 * 4 + reg) * EPI_PAD + nt * 16 + l15] = v[reg];
    }
    {
        int spx = lane >> 2, q = lane & 3;
        float* row = smE + spx * EPI_PAD;
        float v[NK], mx = -1e30f;
#pragma unroll
        for (int k = 0; k < NK; ++k) {
            v[k] = row[4 * k + q] + sbias[4 * k + q];
            mx = fmaxf(mx, v[k]);
        }
        float ssum = 0.f;
#pragma unroll
        for (int k = 0; k < NK; ++k) { v[k] = __expf(v[k] - mx); ssum += v[k]; }
        float inv = 1.0f / ssum;
#pragma unroll
        for (int k = 0; k < NK; ++k) row[4 * k + q] = v[k] * inv;
    }
#pragma unroll
    for (int i = 0; i < 7; ++i) {
        int idx = i * 64 + lane;                // 400 slots
        if (idx < 400) {
            int spx = idx / 25, f4 = idx % 25;
            int rr = 2 * wv + (spx >> 3), cc2 = spx & 7;
            size_t p = (size_t)(h0 + rr) * 64 + (w0 + cc2);
            const float* sp = smE + spx * EPI_PAD + f4 * 4;
            unsigned u0 = (unsigned)f2bf(sp[0]) | ((unsigned)f2bf(sp[1]) << 16);
            unsigned u1 = (unsigned)f2bf(sp[2]) | ((unsigned)f2bf(sp[3]) << 16);
            *(uint2*)(maskn + p * 100 + f4 * 4) = make_uint2(u0, u1);
        }
    }
}

// ---------------------------------------------------------------------------
// Kernel 4: reassembly v6. Structure = round-1 verified; ONLY change: the
// mask is no longer staged in LDS. Each thread reads its OWN px's contiguous
// 200 B mask row from global as 25 uint2 (8B-aligned: 200 % 8 == 0). A
// wave's rows span 12.8 KB -> L1-resident; mask is 3.3 MB, L2-resident with
// 16x cg reuse + XCD swizzle. Deletes: 1600-slot staging loop (/25 %25
// divides), ms LDS array (LDS 24.6 -> 11.5 KB), 50 ds_read_b32/thread --
// targets the LDS-throughput floor (~20 us/CU of LDS data cycles before).
#define XSTR2 20
__global__ __launch_bounds__(256, 6) void k_reassemble(const float* __restrict__ x,
        const unsigned short* __restrict__ mask, float* __restrict__ out) {
    __shared__ __align__(16) float xs[144 * XSTR2];   // 11,520 B
    int flat = blockIdx.x;
    int nf = (flat & 7) * 512 + (flat >> 3);    // XCD-contiguous work ids
    int tile = nf & 63, cg = (nf >> 6) & 15, n = nf >> 10;
    int h0 = (tile >> 3) * 8, w0 = (tile & 7) * 8;
    int tid = threadIdx.x;

    // stage x halo: 12x12 px x 16 c, float2 (gw base even -> pairs never
    // straddle the zero-pad boundary), zero OOB
    const float* xb = x + ((size_t)n * C_IN + cg * 16) * HW;
#pragma unroll
    for (int i = 0; i < 5; ++i) {
        int s = i * 256 + tid;                  // 16c * 12r * 6 pairs = 1152
        if (s < 1152) {
            int c = s / 72, rem = s % 72;
            int r = rem / 6, j = rem % 6;
            int gh = h0 - 2 + r, gw = w0 - 2 + j * 2;
            float2 v = make_float2(0.f, 0.f);
            if ((unsigned)gh < 64u && (unsigned)gw < 64u)
                v = *(const float2*)(xb + (size_t)c * HW + gh * W_DIM + gw);
            int px = r * 12 + j * 2;
            xs[px * XSTR2 + c]       = v.x;
            xs[(px + 1) * XSTR2 + c] = v.y;
        }
    }
    __syncthreads();

    int px = tid & 63, w = tid >> 6;            // lane = out px, wave = 4-ch slice
    int wx = px & 7, hy = px >> 3;
    // own mask row, straight from global (L1-resident within the wave)
    const unsigned short* mrow = mask + (size_t)n * HW * 100
                               + (size_t)((h0 + hy) * W_DIM + (w0 + wx)) * 100;
    f32x4 acc0 = {0.f, 0.f, 0.f, 0.f}, acc1 = {0.f, 0.f, 0.f, 0.f};
    f32x4 acc2 = {0.f, 0.f, 0.f, 0.f}, acc3 = {0.f, 0.f, 0.f, 0.f};
#pragma unroll
    for (int di = 0; di < 5; ++di) {
        uint2 mq0 = *(const uint2*)(mrow + (di * 5 + 0) * 4);
        uint2 mq1 = *(const uint2*)(mrow + (di * 5 + 1) * 4);
        uint2 mq2 = *(const uint2*)(mrow + (di * 5 + 2) * 4);
        uint2 mq3 = *(const uint2*)(mrow + (di * 5 + 3) * 4);
        uint2 mq4 = *(const uint2*)(mrow + (di * 5 + 4) * 4);
#pragma unroll
        for (int dj = 0; dj < 5; ++dj) {
            uint2 mw = (dj == 0) ? mq0 : (dj == 1) ? mq1 : (dj == 2) ? mq2
                     : (dj == 3) ? mq3 : mq4;
            f32x4 xv = *(const f32x4*)(xs + ((hy + di) * 12 + wx + dj) * XSTR2 + w * 4);
            acc0 += xv * bflo2f(mw.x);
            acc1 += xv * bfhi2f(mw.x);
            acc2 += xv * bflo2f(mw.y);
            acc3 += xv * bfhi2f(mw.y);
        }
    }
#pragma unroll
    for (int u = 0; u < 4; ++u) {
        float* ob = out + (((size_t)n * C_IN + cg * 16 + w * 4 + u) * 128 + 2 * (h0 + hy)) * 128
                        + 2 * (w0 + wx);
        *(float2*)(ob)       = make_float2(acc0[u], acc1[u]);
        *(float2*)(ob + 128) = make_float2(acc2[u], acc3[u]);
    }
}

// ---------------------------------------------------------------------------
extern "C" void kernel_launch(void* const* d_in, const int* in_sizes, int n_in,
                              void* d_out, int out_size, void* d_ws, size_t ws_size,
                              hipStream_t stream) {
    const float* x      = (const float*)d_in[0];
    const float* w_comp = (const float*)d_in[1];
    const float* b_comp = (const float*)d_in[2];
    const float* w_enc  = (const float*)d_in[3];
    const float* b_enc  = (const float*)d_in[4];
    float* out = (float*)d_out;
    unsigned char* ws = (unsigned char*)d_ws;

    unsigned short* comp  = (unsigned short*)(ws);             // 4*4096*64*2  = 2,097,152 B
    unsigned short* wtb   = (unsigned short*)(ws + 2097152);   // 9*112*64*2   =   129,024 B
    unsigned short* maskp = (unsigned short*)(ws + 2226176);   // 4*4096*100*2 = 3,276,800 B

    hipLaunchKernelGGL(k_compress,   dim3(508),      dim3(256), 0, stream,
                       x, w_comp, b_comp, w_enc, comp, wtb);
    hipLaunchKernelGGL(k_enc,        dim3(64, 4),    dim3(256), 0, stream,
                       comp, wtb, b_enc, maskp);
    hipLaunchKernelGGL(k_reassemble, dim3(4096),     dim3(256), 0, stream,
                       x, maskp, out);
}